// Round 8
// baseline (457.608 us; speedup 1.0000x reference)
//
#include <hip/hip_runtime.h>

#define DIM 1024
#define NH 16
#define HD 64
#define BB 2
#define LL 2048
#define BL (BB*LL)     // 4096
#define NQKV (3*DIM)   // 3072

typedef __bf16 bf16;
typedef __bf16 bf16x4 __attribute__((ext_vector_type(4)));
typedef __bf16 bf16x8 __attribute__((ext_vector_type(8)));
typedef float  f32x4  __attribute__((ext_vector_type(4)));

// 0.125 * log2(e): fold head-dim scale + base-2 conversion into Q
#define QSCALE 0.1803368801111204f

typedef __attribute__((address_space(3))) unsigned int lds_u32;
typedef __attribute__((address_space(1))) unsigned int glb_u32;

// async global->LDS, 16B per lane. LDS dest = wave-uniform base + lane*16.
__device__ __forceinline__ void gld_lds16(const bf16* g, bf16* l) {
    __builtin_amdgcn_global_load_lds((const glb_u32*)g, (lds_u32*)l, 16, 0, 0);
}

// One kernel for all three fp32->bf16 conversions.
#define C0 (BL*DIM/4)      // x     : 1048576 float4
#define C1 (NQKV*DIM/4)    // w_qkv :  786432
#define C2 (DIM*DIM/4)     // w_proj:  262144
__global__ __launch_bounds__(256) void cvt_all(const float* __restrict__ x,
        const float* __restrict__ wq, const float* __restrict__ wp,
        bf16* __restrict__ xb, bf16* __restrict__ wqb, bf16* __restrict__ wpb) {
    int i = blockIdx.x * 256 + threadIdx.x;
    const float* in; bf16* out; int j;
    if (i < C0)            { in = x;  out = xb;  j = i; }
    else if (i < C0 + C1)  { in = wq; out = wqb; j = i - C0; }
    else                   { in = wp; out = wpb; j = i - C0 - C1; }
    float4 f = ((const float4*)in)[j];
    bf16x4 o = { (bf16)f.x, (bf16)f.y, (bf16)f.z, (bf16)f.w };
    ((bf16x4*)out)[j] = o;
}

// QKV GEMM: 128x128 tile, BK=64, XOR-swizzled LDS, operand-swapped MFMA
// (A-op = W rows) -> vectorized Q/K stores, lane-contiguous V stores.
// 768 blocks = 3/CU: cross-block overlap covers the barrier drain (m97).
__global__ __launch_bounds__(256, 3) void gemm_qkv(
        const bf16* __restrict__ A, const bf16* __restrict__ W,
        bf16* __restrict__ Qb, bf16* __restrict__ Kb, bf16* __restrict__ VTb) {
    __shared__ bf16 As[128][64];   // x tile, swizzled: LDS[r][c] = glb[r][c^(r&7)]
    __shared__ bf16 Bs[128][64];   // W tile, swizzled
    const int tid = threadIdx.x;
    const int w = tid >> 6, lane = tid & 63, quad = lane >> 4, l16 = lane & 15;
    const int n0 = blockIdx.x * 128, m0 = blockIdx.y * 128;
    const int wm = (w & 1) * 64, wn = (w >> 1) * 64;
    f32x4 acc[4][4] = {};   // acc[tm(n)][tn(m)]
    for (int k0 = 0; k0 < DIM; k0 += 64) {
        #pragma unroll
        for (int i = 0; i < 4; ++i) {        // 1024 chunks per tensor, 4/thread
            int cb = w * 256 + i * 64;       // wave-uniform chunk base
            int gc = cb + lane;
            int r = gc >> 3;
            int cs = (gc & 7) ^ (r & 7);     // swizzled source chunk
            gld_lds16(A + (size_t)(m0 + r) * DIM + k0 + cs*8, &As[0][0] + cb * 8);
            gld_lds16(W + (size_t)(n0 + r) * DIM + k0 + cs*8, &Bs[0][0] + cb * 8);
        }
        __syncthreads();
        #pragma unroll
        for (int kc = 0; kc < 2; ++kc) {
            bf16x8 af[4], bfr[4];
            #pragma unroll
            for (int t = 0; t < 4; ++t) {
                int rw = wn + t*16 + l16;                 // W row (n)
                int cw = (kc*4 + quad) ^ (rw & 7);
                af[t] = *(const bf16x8*)(&Bs[0][0] + rw*64 + cw*8);
                int rx = wm + t*16 + l16;                 // x row (m)
                int cx = (kc*4 + quad) ^ (rx & 7);
                bfr[t] = *(const bf16x8*)(&As[0][0] + rx*64 + cx*8);
            }
            #pragma unroll
            for (int tm = 0; tm < 4; ++tm)
                #pragma unroll
                for (int tn = 0; tn < 4; ++tn)
                    acc[tm][tn] = __builtin_amdgcn_mfma_f32_16x16x32_bf16(
                                      af[tm], bfr[tn], acc[tm][tn], 0, 0, 0);
        }
        __syncthreads();
    }
    // D layout (swapped): row quad*4+r -> n, col l16 -> m
    const int which = n0 >> 10;   // uniform per block
    #pragma unroll
    for (int tm = 0; tm < 4; ++tm) {
        int nb = n0 + wn + tm*16 + quad*4;       // n base for this lane (r=0..3)
        int rem = nb & 1023, h = rem >> 6, db = rem & 63;
        #pragma unroll
        for (int tn = 0; tn < 4; ++tn) {
            int m = m0 + wm + tn*16 + l16;
            int b = m >> 11, l = m & 2047, bh = (b << 4) | h;
            if (which == 0) {
                bf16x4 q4 = { (bf16)(acc[tm][tn][0] * QSCALE),
                              (bf16)(acc[tm][tn][1] * QSCALE),
                              (bf16)(acc[tm][tn][2] * QSCALE),
                              (bf16)(acc[tm][tn][3] * QSCALE) };
                *(bf16x4*)(Qb + ((size_t)bh << 17) + ((size_t)l << 6) + db) = q4;
            } else if (which == 1) {
                bf16x4 k4 = { (bf16)acc[tm][tn][0], (bf16)acc[tm][tn][1],
                              (bf16)acc[tm][tn][2], (bf16)acc[tm][tn][3] };
                *(bf16x4*)(Kb + ((size_t)bh << 17) + ((size_t)l << 6) + db) = k4;
            } else {
                #pragma unroll
                for (int r = 0; r < 4; ++r)   // lanes contiguous in l: 32B chunks
                    VTb[((size_t)bh << 17) + ((size_t)(db + r) << 11) + l] =
                        (bf16)acc[tm][tn][r];
            }
        }
    }
}

// proj: REVERTED to the R5-proven version. 128(M)x64(N), BK=64, swizzled,
// operand-swapped, double-buffered with 1-iter lookahead, 512 blocks = 2/CU.
// (R7's 128x128 variant had grid 256 = 1 block/CU: the single-buffer drain
// was fully exposed with no cross-block overlap -> +12us regression.)
__global__ __launch_bounds__(256, 3) void gemm_proj(
        const bf16* __restrict__ A, const bf16* __restrict__ W,
        const float* __restrict__ bias, float* __restrict__ out) {
    __shared__ bf16 As[2][128][64];   // 32 KB
    __shared__ bf16 Bs[2][64][64];    // 16 KB
    const int tid = threadIdx.x;
    const int w = tid >> 6, lane = tid & 63, quad = lane >> 4, l16 = lane & 15;
    const int n0 = blockIdx.x * 64, m0 = blockIdx.y * 128;
    const int wm = (w & 1) * 64, wn = (w >> 1) * 32;
    f32x4 acc[2][4] = {};   // acc[tm(n)][tn(m)]

    auto stage = [&](int k0, int buf) {
        #pragma unroll
        for (int i = 0; i < 4; ++i) {        // A: 1024 chunks, 4/thread
            int cb = w * 256 + i * 64;
            int gc = cb + lane;
            int r = gc >> 3;
            int cs = (gc & 7) ^ (r & 7);
            gld_lds16(A + (size_t)(m0 + r) * DIM + k0 + cs*8,
                      &As[buf][0][0] + cb * 8);
        }
        #pragma unroll
        for (int i = 0; i < 2; ++i) {        // B: 512 chunks, 2/thread
            int cb = w * 128 + i * 64;
            int gc = cb + lane;
            int r = gc >> 3;
            int cs = (gc & 7) ^ (r & 7);
            gld_lds16(W + (size_t)(n0 + r) * DIM + k0 + cs*8,
                      &Bs[buf][0][0] + cb * 8);
        }
    };

    stage(0, 0);
    for (int ks = 0; ks < 16; ++ks) {
        const int cur = ks & 1;
        __syncthreads();                  // stage(ks) landed; buf^1 reads done
        if (ks < 15) stage((ks + 1) * 64, cur ^ 1);
        #pragma unroll
        for (int kc = 0; kc < 2; ++kc) {
            bf16x8 af[2], bfr[4];
            #pragma unroll
            for (int t = 0; t < 2; ++t) {
                int rw = wn + t*16 + l16;
                int cw = (kc*4 + quad) ^ (rw & 7);
                af[t] = *(const bf16x8*)(&Bs[cur][0][0] + rw*64 + cw*8);
            }
            #pragma unroll
            for (int t = 0; t < 4; ++t) {
                int rx = wm + t*16 + l16;
                int cx = (kc*4 + quad) ^ (rx & 7);
                bfr[t] = *(const bf16x8*)(&As[cur][0][0] + rx*64 + cx*8);
            }
            #pragma unroll
            for (int tm = 0; tm < 2; ++tm)
                #pragma unroll
                for (int tn = 0; tn < 4; ++tn)
                    acc[tm][tn] = __builtin_amdgcn_mfma_f32_16x16x32_bf16(
                                      af[tm], bfr[tn], acc[tm][tn], 0, 0, 0);
        }
    }
    #pragma unroll
    for (int tm = 0; tm < 2; ++tm) {
        int nb = n0 + wn + tm*16 + quad*4;
        float4 b4 = *(const float4*)&bias[nb];
        #pragma unroll
        for (int tn = 0; tn < 4; ++tn) {
            int m = m0 + wm + tn*16 + l16;
            float4 o4 = { acc[tm][tn][0] + b4.x, acc[tm][tn][1] + b4.y,
                          acc[tm][tn][2] + b4.z, acc[tm][tn][3] + b4.w };
            *(float4*)(out + (size_t)m * DIM + nb) = o4;
        }
    }
}

// Flash attention: QBLK=256, KVBLK=128, now 16 WAVES (1024 threads) with
// 4-WAY kv-split: waves = 4 q-quarters (qw) x 4 kv-quarters (kvh, 32 kv rows
// each). R5/R6 counters showed MfmaUtil ~= VALUBusy ~= 27%, summing to ~53%:
// with 2 barrier-locked waves/SIMD the MFMA and exp phases ALTERNATE instead
// of overlapping. 4 waves/SIMD doubles scheduler TLP so one wave's exp runs
// under another's MFMA (m114 mechanism). Total per-CU LDS reads and staging
// are UNCHANGED (each wave reads only its kv-quarter -- R6's amortization
// lesson respected); per-wave MFMA/exp work halves. Fragment maps are the
// verified R5 maps under kk->(kvh&1), subtile kvh>>1. Epilogue: 2-stage
// pairwise tree combine of the 4 (O,l) partials via LDS.
__global__ __launch_bounds__(1024, 4) void attn(
        const bf16* __restrict__ Qb, const bf16* __restrict__ Kb,
        const bf16* __restrict__ VTb, bf16* __restrict__ AO) {
    __shared__ __align__(16) char smem[66560];   // Ks 32KB | VTs 32KB | Lred 1KB
    bf16* KsP  = (bf16*)smem;                    // [buf][sub][64][64]
    bf16* VTsP = (bf16*)(smem + 32768);          // [buf][sub][64][64]
    const int tid = threadIdx.x;
    const int w = tid >> 6, lane = tid & 63, quad = lane >> 4, l16 = lane & 15;
    const int qw = w & 3, kvh = w >> 2;          // q-quarter, kv-quarter (0..3)
    // Bijective XCD swizzle (nwg=256, 256%8==0): XCD x gets bh in [4x, 4x+3].
    const int linear = blockIdx.y * 8 + blockIdx.x;
    const int swz = (linear & 7) * 32 + (linear >> 3);
    const int qt = swz & 7, bh = swz >> 3;
    const bf16* Qg = Qb + ((size_t)bh << 17) + (size_t)(qt * 256) * 64;
    const bf16* Kg = Kb + ((size_t)bh << 17);
    const bf16* Vg = VTb + ((size_t)bh << 17);

    bf16x8 aq[4][2];   // aq[sub][kd]: Q[q=qw*64+sub*16+l16][d=kd*32+quad*8+..]
    #pragma unroll
    for (int sub = 0; sub < 4; ++sub)
        #pragma unroll
        for (int kd = 0; kd < 2; ++kd)
            aq[sub][kd] = *(const bf16x8*)(Qg + (size_t)(qw*64 + sub*16 + l16) * 64
                                           + kd*32 + quad*8);

    bf16x8 onesf = {};
    if (l16 == 0)
        #pragma unroll
        for (int j = 0; j < 8; ++j) onesf[j] = (bf16)1.0f;

    f32x4 oacc[4][4] = {};         // [sub][nt]: O[q=sub*16+quad*4+r][d=nt*16+l16]
    f32x4 lacc[4] = {};            // row-sums, valid at l16==0 lanes
    const f32x4 zero4 = {};
    bf16x8 ap[4];                  // P regs: [sub], packed kt, PV'd kt+1

    // 1024 threads stage the full 128x64 tile (2 subtiles) in one pass.
    auto stageK = [&](int kt, int buf) {
        int sub = tid >> 9, tl = tid & 511;              // wave-uniform sub
        int r = tl >> 3;
        int cs = (tl & 7) ^ (r & 7) ^ ((r >> 3) & 7) ^ ((r & 1) << 2);   // fK
        gld_lds16(Kg + (size_t)(kt*128 + sub*64 + r) * 64 + cs*8,
                  KsP + (buf*2 + sub) * 4096 + tl*8);
    };
    auto stageV = [&](int kt, int buf) {
        int sub = tid >> 9, tl = tid & 511;
        int r = tl >> 3;
        int cs = (tl & 7) ^ (r & 7) ^ ((r >> 3) & 7);                    // fV
        gld_lds16(Vg + (size_t)r * 2048 + kt*128 + sub*64 + cs*8,
                  VTsP + (buf*2 + sub) * 4096 + tl*8);
    };
    // PV for register P-frags 'ap' (this wave's kv-quarter)
    auto pv = [&](int pbuf) {
        __builtin_amdgcn_s_setprio(1);
        #pragma unroll
        for (int nt = 0; nt < 4; ++nt) {
            int row = nt*16 + l16;                      // d-dim row of VT
            int cp = ((kvh & 1)*4 + quad) ^ (row & 7) ^ ((row >> 3) & 7);
            bf16x8 bv = *(const bf16x8*)(VTsP + (pbuf*2 + (kvh >> 1)) * 4096
                                         + row*64 + cp*8);
            #pragma unroll
            for (int sub = 0; sub < 4; ++sub)
                oacc[sub][nt] = __builtin_amdgcn_mfma_f32_16x16x32_bf16(
                                    ap[sub], bv, oacc[sub][nt], 0, 0, 0);
        }
        #pragma unroll
        for (int sub = 0; sub < 4; ++sub)
            lacc[sub] = __builtin_amdgcn_mfma_f32_16x16x32_bf16(
                            ap[sub], onesf, lacc[sub], 0, 0, 0);
        __builtin_amdgcn_s_setprio(0);
    };

    // One pipeline step (128 kv). Barrier: K(kt)+V(kt-1) staging landed (loads
    // issued a full iteration ago); reads of buffers being overwritten done.
    auto body = [&](int kt, int cur) {
        __syncthreads();
        if (kt < 15) stageK(kt + 1, cur ^ 1);
        stageV(kt, cur);                      // read at iter kt+1 (or epilogue)

        // PV(kt-1): register P (old ap) + VTs[cur^1]
        if (kt > 0) pv(cur ^ 1);

        // S^T(kt) from Ks[cur][kvh>>1], rows (kvh&1)*32..+31 (permuted), B=aq
        f32x4 s[4][2];   // [sub][u]
        __builtin_amdgcn_s_setprio(1);
        #pragma unroll
        for (int u = 0; u < 2; ++u) {
            int rk = (kvh & 1)*32 + ((l16 >> 2) << 3) + u*4 + (l16 & 3);
            int f = (rk & 7) ^ ((rk >> 3) & 7) ^ ((rk & 1) << 2);
            const bf16* kb = KsP + (cur*2 + (kvh >> 1)) * 4096 + rk*64;
            bf16x8 kf0 = *(const bf16x8*)(kb + ((0*4 + quad) ^ f)*8);
            bf16x8 kf1 = *(const bf16x8*)(kb + ((1*4 + quad) ^ f)*8);
            #pragma unroll
            for (int sub = 0; sub < 4; ++sub) {
                s[sub][u] = __builtin_amdgcn_mfma_f32_16x16x32_bf16(
                                kf0, aq[sub][0], zero4, 0, 0, 0);
                s[sub][u] = __builtin_amdgcn_mfma_f32_16x16x32_bf16(
                                kf1, aq[sub][1], s[sub][u], 0, 0, 0);
            }
        }
        __builtin_amdgcn_s_setprio(0);

        // exp2 + pack P(kt); lane (quad,l16) holds
        // P[q=l16][kv = kvh*32 + quad*8 + u*4 + r].
        #pragma unroll
        for (int sub = 0; sub < 4; ++sub) {
            bf16x8 p;
            #pragma unroll
            for (int u = 0; u < 2; ++u)
                #pragma unroll
                for (int r = 0; r < 4; ++r)
                    p[u*4 + r] = (bf16)__builtin_amdgcn_exp2f(s[sub][u][r]);
            ap[sub] = p;
        }
    };

    stageK(0, 0);
    for (int kt2 = 0; kt2 < 16; kt2 += 2) {
        body(kt2,     0);
        body(kt2 + 1, 1);
    }
    __syncthreads();   // V(15) staging landed for all waves
    pv(1);             // final PV(15)

    // Tree-combine the 4 kv-quarter partials per q-quarter, in 2 qw-groups.
    // Stage A: kvh odd -> slot[(qw&1)*2 + (kvh>>1)] (4 x 16KB = 64KB);
    //          kvh even adds its pair. Stage B: kvh==2 -> slot[(qw&1)*2];
    //          kvh==0 adds and stores.
    float* OredF = (float*)smem;            // [slot4][sub4][row16][d64] f32
    float* LredF = (float*)(smem + 65536);  // [slot4][sub4][row16] f32
    const int b = bh >> 4, h = bh & 15;
    #pragma unroll
    for (int t = 0; t < 2; ++t) {
        const bool grp = (qw >> 1) == t;
        __syncthreads();
        if (grp && (kvh & 1)) {
            int slot = (qw & 1)*2 + (kvh >> 1);
            #pragma unroll
            for (int sub = 0; sub < 4; ++sub)
                #pragma unroll
                for (int nt = 0; nt < 4; ++nt)
                    #pragma unroll
                    for (int r = 0; r < 4; ++r)
                        OredF[((slot*4 + sub)*16 + quad*4 + r)*64 + nt*16 + l16]
                            = oacc[sub][nt][r];
            if (l16 == 0)
                #pragma unroll
                for (int sub = 0; sub < 4; ++sub)
                    #pragma unroll
                    for (int r = 0; r < 4; ++r)
                        LredF[(slot*4 + sub)*16 + quad*4 + r] = lacc[sub][r];
        }
        __syncthreads();
        if (grp && !(kvh & 1)) {
            int slot = (qw & 1)*2 + (kvh >> 1);
            #pragma unroll
            for (int sub = 0; sub < 4; ++sub)
                #pragma unroll
                for (int nt = 0; nt < 4; ++nt)
                    #pragma unroll
                    for (int r = 0; r < 4; ++r)
                        oacc[sub][nt][r] +=
                            OredF[((slot*4 + sub)*16 + quad*4 + r)*64 + nt*16 + l16];
            if (l16 == 0)
                #pragma unroll
                for (int sub = 0; sub < 4; ++sub)
                    #pragma unroll
                    for (int r = 0; r < 4; ++r)
                        lacc[sub][r] += LredF[(slot*4 + sub)*16 + quad*4 + r];
        }
        __syncthreads();
        if (grp && kvh == 2) {
            int slot = (qw & 1)*2;
            #pragma unroll
            for (int sub = 0; sub < 4; ++sub)
                #pragma unroll
                for (int nt = 0; nt < 4; ++nt)
                    #pragma unroll
                    for (int r = 0; r < 4; ++r)
                        OredF[((slot*4 + sub)*16 + quad*4 + r)*64 + nt*16 + l16]
                            = oacc[sub][nt][r];
            if (l16 == 0)
                #pragma unroll
                for (int sub = 0; sub < 4; ++sub)
                    #pragma unroll
                    for (int r = 0; r < 4; ++r)
                        LredF[(slot*4 + sub)*16 + quad*4 + r] = lacc[sub][r];
        }
        __syncthreads();
        if (grp && kvh == 0) {
            int slot = (qw & 1)*2;
            #pragma unroll
            for (int sub = 0; sub < 4; ++sub)
                #pragma unroll
                for (int nt = 0; nt < 4; ++nt)
                    #pragma unroll
                    for (int r = 0; r < 4; ++r)
                        oacc[sub][nt][r] +=
                            OredF[((slot*4 + sub)*16 + quad*4 + r)*64 + nt*16 + l16];
            if (l16 == 0)
                #pragma unroll
                for (int sub = 0; sub < 4; ++sub)
                    #pragma unroll
                    for (int r = 0; r < 4; ++r)
                        lacc[sub][r] += LredF[(slot*4 + sub)*16 + quad*4 + r];
            #pragma unroll
            for (int sub = 0; sub < 4; ++sub)
                #pragma unroll
                for (int r = 0; r < 4; ++r) {
                    float l = __shfl(lacc[sub][r], quad * 16, 64);
                    float inv = 1.0f / l;
                    int lq = qt*256 + qw*64 + sub*16 + quad*4 + r;
                    size_t rowbase = ((size_t)(b * 2048 + lq)) * DIM + h * 64;
                    #pragma unroll
                    for (int nt = 0; nt < 4; ++nt)
                        AO[rowbase + nt*16 + l16] = (bf16)(oacc[sub][nt][r] * inv);
                }
        }
    }
}

extern "C" void kernel_launch(void* const* d_in, const int* in_sizes, int n_in,
                              void* d_out, int out_size, void* d_ws, size_t ws_size,
                              hipStream_t stream) {
    const float* x      = (const float*)d_in[0];
    const float* w_qkv  = (const float*)d_in[1];
    const float* w_proj = (const float*)d_in[2];
    const float* b_proj = (const float*)d_in[3];
    float* out = (float*)d_out;
    char* ws = (char*)d_ws;

    bf16* xb  = (bf16*)(ws);                    // 8 MB
    bf16* wqb = (bf16*)(ws + ( 8u << 20));      // 6 MB
    bf16* wpb = (bf16*)(ws + (14u << 20));      // 2 MB
    bf16* Qb  = (bf16*)(ws + (16u << 20));      // 8 MB [bh][l][d]
    bf16* Kb  = (bf16*)(ws + (24u << 20));      // 8 MB [bh][l][d]
    bf16* VTb = (bf16*)(ws + (32u << 20));      // 8 MB [bh][d][l]
    bf16* AOb = (bf16*)(ws + (40u << 20));      // 8 MB [b*l][h*d]

    cvt_all<<<(C0 + C1 + C2) / 256, 256, 0, stream>>>(x, w_qkv, w_proj, xb, wqb, wpb);
    gemm_qkv<<<dim3(NQKV/128, BL/128), 256, 0, stream>>>(xb, wqb, Qb, Kb, VTb);
    attn<<<dim3(LL/256, BB*NH),        1024, 0, stream>>>(Qb, Kb, VTb, AOb);
    gemm_proj<<<dim3(DIM/64, BL/128),  256, 0, stream>>>(AOb, wpb, b_proj, out);
}

// Round 9
// 171.620 us; speedup vs baseline: 2.6664x; 2.6664x over previous
//
#include <hip/hip_runtime.h>

#define DIM 1024
#define NH 16
#define HD 64
#define BB 2
#define LL 2048
#define BL (BB*LL)     // 4096
#define NQKV (3*DIM)   // 3072

typedef __bf16 bf16;
typedef __bf16 bf16x4 __attribute__((ext_vector_type(4)));
typedef __bf16 bf16x8 __attribute__((ext_vector_type(8)));
typedef float  f32x4  __attribute__((ext_vector_type(4)));

// 0.125 * log2(e): fold head-dim scale + base-2 conversion into Q
#define QSCALE 0.1803368801111204f

typedef __attribute__((address_space(3))) unsigned int lds_u32;
typedef __attribute__((address_space(1))) unsigned int glb_u32;

// async global->LDS, 16B per lane. LDS dest = wave-uniform base + lane*16.
__device__ __forceinline__ void gld_lds16(const bf16* g, bf16* l) {
    __builtin_amdgcn_global_load_lds((const glb_u32*)g, (lds_u32*)l, 16, 0, 0);
}

// One kernel for all three fp32->bf16 conversions.
#define C0 (BL*DIM/4)      // x     : 1048576 float4
#define C1 (NQKV*DIM/4)    // w_qkv :  786432
#define C2 (DIM*DIM/4)     // w_proj:  262144
__global__ __launch_bounds__(256) void cvt_all(const float* __restrict__ x,
        const float* __restrict__ wq, const float* __restrict__ wp,
        bf16* __restrict__ xb, bf16* __restrict__ wqb, bf16* __restrict__ wpb) {
    int i = blockIdx.x * 256 + threadIdx.x;
    const float* in; bf16* out; int j;
    if (i < C0)            { in = x;  out = xb;  j = i; }
    else if (i < C0 + C1)  { in = wq; out = wqb; j = i - C0; }
    else                   { in = wp; out = wpb; j = i - C0 - C1; }
    float4 f = ((const float4*)in)[j];
    bf16x4 o = { (bf16)f.x, (bf16)f.y, (bf16)f.z, (bf16)f.w };
    ((bf16x4*)out)[j] = o;
}

// QKV GEMM: 128x128 tile, BK=64, XOR-swizzled LDS, operand-swapped MFMA
// (A-op = W rows) -> vectorized Q/K stores, lane-contiguous V stores.
// 768 blocks = 3/CU: cross-block overlap covers the barrier drain (m97).
__global__ __launch_bounds__(256, 3) void gemm_qkv(
        const bf16* __restrict__ A, const bf16* __restrict__ W,
        bf16* __restrict__ Qb, bf16* __restrict__ Kb, bf16* __restrict__ VTb) {
    __shared__ bf16 As[128][64];   // x tile, swizzled: LDS[r][c] = glb[r][c^(r&7)]
    __shared__ bf16 Bs[128][64];   // W tile, swizzled
    const int tid = threadIdx.x;
    const int w = tid >> 6, lane = tid & 63, quad = lane >> 4, l16 = lane & 15;
    const int n0 = blockIdx.x * 128, m0 = blockIdx.y * 128;
    const int wm = (w & 1) * 64, wn = (w >> 1) * 64;
    f32x4 acc[4][4] = {};   // acc[tm(n)][tn(m)]
    for (int k0 = 0; k0 < DIM; k0 += 64) {
        #pragma unroll
        for (int i = 0; i < 4; ++i) {        // 1024 chunks per tensor, 4/thread
            int cb = w * 256 + i * 64;       // wave-uniform chunk base
            int gc = cb + lane;
            int r = gc >> 3;
            int cs = (gc & 7) ^ (r & 7);     // swizzled source chunk
            gld_lds16(A + (size_t)(m0 + r) * DIM + k0 + cs*8, &As[0][0] + cb * 8);
            gld_lds16(W + (size_t)(n0 + r) * DIM + k0 + cs*8, &Bs[0][0] + cb * 8);
        }
        __syncthreads();
        #pragma unroll
        for (int kc = 0; kc < 2; ++kc) {
            bf16x8 af[4], bfr[4];
            #pragma unroll
            for (int t = 0; t < 4; ++t) {
                int rw = wn + t*16 + l16;                 // W row (n)
                int cw = (kc*4 + quad) ^ (rw & 7);
                af[t] = *(const bf16x8*)(&Bs[0][0] + rw*64 + cw*8);
                int rx = wm + t*16 + l16;                 // x row (m)
                int cx = (kc*4 + quad) ^ (rx & 7);
                bfr[t] = *(const bf16x8*)(&As[0][0] + rx*64 + cx*8);
            }
            #pragma unroll
            for (int tm = 0; tm < 4; ++tm)
                #pragma unroll
                for (int tn = 0; tn < 4; ++tn)
                    acc[tm][tn] = __builtin_amdgcn_mfma_f32_16x16x32_bf16(
                                      af[tm], bfr[tn], acc[tm][tn], 0, 0, 0);
        }
        __syncthreads();
    }
    // D layout (swapped): row quad*4+r -> n, col l16 -> m
    const int which = n0 >> 10;   // uniform per block
    #pragma unroll
    for (int tm = 0; tm < 4; ++tm) {
        int nb = n0 + wn + tm*16 + quad*4;       // n base for this lane (r=0..3)
        int rem = nb & 1023, h = rem >> 6, db = rem & 63;
        #pragma unroll
        for (int tn = 0; tn < 4; ++tn) {
            int m = m0 + wm + tn*16 + l16;
            int b = m >> 11, l = m & 2047, bh = (b << 4) | h;
            if (which == 0) {
                bf16x4 q4 = { (bf16)(acc[tm][tn][0] * QSCALE),
                              (bf16)(acc[tm][tn][1] * QSCALE),
                              (bf16)(acc[tm][tn][2] * QSCALE),
                              (bf16)(acc[tm][tn][3] * QSCALE) };
                *(bf16x4*)(Qb + ((size_t)bh << 17) + ((size_t)l << 6) + db) = q4;
            } else if (which == 1) {
                bf16x4 k4 = { (bf16)acc[tm][tn][0], (bf16)acc[tm][tn][1],
                              (bf16)acc[tm][tn][2], (bf16)acc[tm][tn][3] };
                *(bf16x4*)(Kb + ((size_t)bh << 17) + ((size_t)l << 6) + db) = k4;
            } else {
                #pragma unroll
                for (int r = 0; r < 4; ++r)   // lanes contiguous in l: 32B chunks
                    VTb[((size_t)bh << 17) + ((size_t)(db + r) << 11) + l] =
                        (bf16)acc[tm][tn][r];
            }
        }
    }
}

// proj: R5-proven version. 128(M)x64(N), BK=64, swizzled, operand-swapped,
// double-buffered with 1-iter lookahead, 512 blocks = 2/CU.
__global__ __launch_bounds__(256, 3) void gemm_proj(
        const bf16* __restrict__ A, const bf16* __restrict__ W,
        const float* __restrict__ bias, float* __restrict__ out) {
    __shared__ bf16 As[2][128][64];   // 32 KB
    __shared__ bf16 Bs[2][64][64];    // 16 KB
    const int tid = threadIdx.x;
    const int w = tid >> 6, lane = tid & 63, quad = lane >> 4, l16 = lane & 15;
    const int n0 = blockIdx.x * 64, m0 = blockIdx.y * 128;
    const int wm = (w & 1) * 64, wn = (w >> 1) * 32;
    f32x4 acc[2][4] = {};   // acc[tm(n)][tn(m)]

    auto stage = [&](int k0, int buf) {
        #pragma unroll
        for (int i = 0; i < 4; ++i) {        // A: 1024 chunks, 4/thread
            int cb = w * 256 + i * 64;
            int gc = cb + lane;
            int r = gc >> 3;
            int cs = (gc & 7) ^ (r & 7);
            gld_lds16(A + (size_t)(m0 + r) * DIM + k0 + cs*8,
                      &As[buf][0][0] + cb * 8);
        }
        #pragma unroll
        for (int i = 0; i < 2; ++i) {        // B: 512 chunks, 2/thread
            int cb = w * 128 + i * 64;
            int gc = cb + lane;
            int r = gc >> 3;
            int cs = (gc & 7) ^ (r & 7);
            gld_lds16(W + (size_t)(n0 + r) * DIM + k0 + cs*8,
                      &Bs[buf][0][0] + cb * 8);
        }
    };

    stage(0, 0);
    for (int ks = 0; ks < 16; ++ks) {
        const int cur = ks & 1;
        __syncthreads();                  // stage(ks) landed; buf^1 reads done
        if (ks < 15) stage((ks + 1) * 64, cur ^ 1);
        #pragma unroll
        for (int kc = 0; kc < 2; ++kc) {
            bf16x8 af[2], bfr[4];
            #pragma unroll
            for (int t = 0; t < 2; ++t) {
                int rw = wn + t*16 + l16;
                int cw = (kc*4 + quad) ^ (rw & 7);
                af[t] = *(const bf16x8*)(&Bs[cur][0][0] + rw*64 + cw*8);
            }
            #pragma unroll
            for (int t = 0; t < 4; ++t) {
                int rx = wm + t*16 + l16;
                int cx = (kc*4 + quad) ^ (rx & 7);
                bfr[t] = *(const bf16x8*)(&As[cur][0][0] + rx*64 + cx*8);
            }
            #pragma unroll
            for (int tm = 0; tm < 2; ++tm)
                #pragma unroll
                for (int tn = 0; tn < 4; ++tn)
                    acc[tm][tn] = __builtin_amdgcn_mfma_f32_16x16x32_bf16(
                                      af[tm], bfr[tn], acc[tm][tn], 0, 0, 0);
        }
    }
    #pragma unroll
    for (int tm = 0; tm < 2; ++tm) {
        int nb = n0 + wn + tm*16 + quad*4;
        float4 b4 = *(const float4*)&bias[nb];
        #pragma unroll
        for (int tn = 0; tn < 4; ++tn) {
            int m = m0 + wm + tn*16 + l16;
            float4 o4 = { acc[tm][tn][0] + b4.x, acc[tm][tn][1] + b4.y,
                          acc[tm][tn][2] + b4.z, acc[tm][tn][3] + b4.w };
            *(float4*)(out + (size_t)m * DIM + nb) = o4;
        }
    }
}

// Flash attention (R5 structure, full revert from the R8 spill disaster:
// 1024-thread blocks cap VGPR at 128 and launch_bounds(1024,4) capped at 64
// -> ~1.5GB scratch traffic). QBLK=256 / 8 waves / 2-way kv-split /
// KVBLK=128, 512 threads, launch_bounds(512,2) -> VGPR ~96, no spill.
// ONE change vs R5: body order is now stage -> S(kt) -> PV(kt-1) -> exp(kt)
// (was stage -> PV -> S -> exp). exp depends on S results; putting the
// 40-MFMA PV burst between S issue and exp consumption lets S complete under
// PV and exp's VALU issue overlap PV's MFMA execution, instead of the wave
// stalling on the S chain then running naked VALU into the barrier.
__global__ __launch_bounds__(512, 2) void attn(
        const bf16* __restrict__ Qb, const bf16* __restrict__ Kb,
        const bf16* __restrict__ VTb, bf16* __restrict__ AO) {
    __shared__ __align__(16) char smem[66048];   // Ks 32KB | VTs 32KB | Lred
    bf16* KsP  = (bf16*)smem;                    // [buf][sub][64][64]
    bf16* VTsP = (bf16*)(smem + 32768);          // [buf][sub][64][64]
    const int tid = threadIdx.x;
    const int w = tid >> 6, lane = tid & 63, quad = lane >> 4, l16 = lane & 15;
    const int qw = w & 3, kvh = w >> 2;          // q-quarter, kv-half
    // Bijective XCD swizzle (nwg=256, 256%8==0): XCD x gets bh in [4x, 4x+3].
    const int linear = blockIdx.y * 8 + blockIdx.x;
    const int swz = (linear & 7) * 32 + (linear >> 3);
    const int qt = swz & 7, bh = swz >> 3;
    const bf16* Qg = Qb + ((size_t)bh << 17) + (size_t)(qt * 256) * 64;
    const bf16* Kg = Kb + ((size_t)bh << 17);
    const bf16* Vg = VTb + ((size_t)bh << 17);

    bf16x8 aq[4][2];   // aq[sub][kd]: Q[q=qw*64+sub*16+l16][d=kd*32+quad*8+..]
    #pragma unroll
    for (int sub = 0; sub < 4; ++sub)
        #pragma unroll
        for (int kd = 0; kd < 2; ++kd)
            aq[sub][kd] = *(const bf16x8*)(Qg + (size_t)(qw*64 + sub*16 + l16) * 64
                                           + kd*32 + quad*8);

    bf16x8 onesf = {};
    if (l16 == 0)
        #pragma unroll
        for (int j = 0; j < 8; ++j) onesf[j] = (bf16)1.0f;

    f32x4 oacc[4][4] = {};         // [sub][nt]: O[q=sub*16+quad*4+r][d=nt*16+l16]
    f32x4 lacc[4] = {};            // row-sums, valid at l16==0 lanes
    const f32x4 zero4 = {};
    bf16x8 ap[4][2];               // P regs: [sub][kk], packed kt, PV'd kt+1

    // 512 threads stage one 16B chunk per subtile (2 subtiles per tensor).
    auto stageK = [&](int kt, int buf) {
        #pragma unroll
        for (int sub = 0; sub < 2; ++sub) {
            int r = tid >> 3;
            int cs = (tid & 7) ^ (r & 7) ^ ((r >> 3) & 7) ^ ((r & 1) << 2); // fK
            gld_lds16(Kg + (size_t)(kt*128 + sub*64 + r) * 64 + cs*8,
                      KsP + (buf*2 + sub) * 4096 + tid*8);
        }
    };
    auto stageV = [&](int kt, int buf) {
        #pragma unroll
        for (int sub = 0; sub < 2; ++sub) {
            int r = tid >> 3;
            int cs = (tid & 7) ^ (r & 7) ^ ((r >> 3) & 7);                  // fV
            gld_lds16(Vg + (size_t)r * 2048 + kt*128 + sub*64 + cs*8,
                      VTsP + (buf*2 + sub) * 4096 + tid*8);
        }
    };
    // PV for register P-frags 'ap' (this wave's kv-half = subtile kvh)
    auto pv = [&](int pbuf) {
        __builtin_amdgcn_s_setprio(1);
        #pragma unroll
        for (int kk = 0; kk < 2; ++kk) {
            #pragma unroll
            for (int nt = 0; nt < 4; ++nt) {
                int row = nt*16 + l16;                      // d-dim row of VT
                int cp = (kk*4 + quad) ^ (row & 7) ^ ((row >> 3) & 7);
                bf16x8 bv = *(const bf16x8*)(VTsP + (pbuf*2 + kvh) * 4096
                                             + row*64 + cp*8);
                #pragma unroll
                for (int sub = 0; sub < 4; ++sub)
                    oacc[sub][nt] = __builtin_amdgcn_mfma_f32_16x16x32_bf16(
                                        ap[sub][kk], bv, oacc[sub][nt], 0, 0, 0);
            }
            #pragma unroll
            for (int sub = 0; sub < 4; ++sub)
                lacc[sub] = __builtin_amdgcn_mfma_f32_16x16x32_bf16(
                                ap[sub][kk], onesf, lacc[sub], 0, 0, 0);
        }
        __builtin_amdgcn_s_setprio(0);
    };

    // One pipeline step (128 kv). Barrier: K(kt)+V(kt-1) staging landed (loads
    // issued a full iteration ago); reads of buffers being overwritten done.
    auto body = [&](int kt, int cur) {
        __syncthreads();
        if (kt < 15) stageK(kt + 1, cur ^ 1);
        stageV(kt, cur);                      // read at iter kt+1 (or epilogue)

        // S^T(kt) FIRST: A = K-frag (permuted rows, this kv-half), B = aq
        f32x4 s[4][2][2];   // [sub][kk][u]
        __builtin_amdgcn_s_setprio(1);
        #pragma unroll
        for (int kk = 0; kk < 2; ++kk)
            #pragma unroll
            for (int u = 0; u < 2; ++u) {
                int rk = kk*32 + ((l16 >> 2) << 3) + u*4 + (l16 & 3);
                int f = (rk & 7) ^ ((rk >> 3) & 7) ^ ((rk & 1) << 2);
                const bf16* kb = KsP + (cur*2 + kvh) * 4096 + rk*64;
                bf16x8 kf0 = *(const bf16x8*)(kb + ((0*4 + quad) ^ f)*8);
                bf16x8 kf1 = *(const bf16x8*)(kb + ((1*4 + quad) ^ f)*8);
                #pragma unroll
                for (int sub = 0; sub < 4; ++sub) {
                    s[sub][kk][u] = __builtin_amdgcn_mfma_f32_16x16x32_bf16(
                                        kf0, aq[sub][0], zero4, 0, 0, 0);
                    s[sub][kk][u] = __builtin_amdgcn_mfma_f32_16x16x32_bf16(
                                        kf1, aq[sub][1], s[sub][kk][u], 0, 0, 0);
                }
            }
        __builtin_amdgcn_s_setprio(0);

        // PV(kt-1): register P (old ap) + VTs[cur^1]. Independent of S(kt);
        // S results complete under this MFMA burst.
        if (kt > 0) pv(cur ^ 1);

        // exp2 + pack P(kt); overlaps PV's MFMA execution (separate pipes).
        // Lane (quad,l16) holds P[q=l16][kv = kvh*64 + kk*32 + quad*8 + u*4+r].
        #pragma unroll
        for (int sub = 0; sub < 4; ++sub)
            #pragma unroll
            for (int kk = 0; kk < 2; ++kk) {
                bf16x8 p;
                #pragma unroll
                for (int u = 0; u < 2; ++u)
                    #pragma unroll
                    for (int r = 0; r < 4; ++r)
                        p[u*4 + r] = (bf16)__builtin_amdgcn_exp2f(s[sub][kk][u][r]);
                ap[sub][kk] = p;
            }
    };

    stageK(0, 0);
    for (int kt2 = 0; kt2 < 16; kt2 += 2) {
        body(kt2,     0);
        body(kt2 + 1, 1);
    }
    __syncthreads();   // V(15) staging landed for all waves
    pv(1);             // final PV(15)

    // Combine kv-halves: wave w+4 adds into wave w via LDS (staging reuse).
    // Two rounds of 2 writer-waves (2 x 16KB = 32KB fits the K region).
    float* OredF = (float*)smem;            // [slot2][sub4][row16][d64]
    float* LredF = (float*)(smem + 32768);  // [slot2][sub4][row16]
    const int b = bh >> 4, h = bh & 15;
    #pragma unroll
    for (int t = 0; t < 2; ++t) {
        __syncthreads();
        if (kvh == 1 && (qw >> 1) == t) {
            int slot = qw & 1;
            #pragma unroll
            for (int sub = 0; sub < 4; ++sub)
                #pragma unroll
                for (int nt = 0; nt < 4; ++nt)
                    #pragma unroll
                    for (int r = 0; r < 4; ++r)
                        OredF[((slot*4 + sub)*16 + quad*4 + r)*64 + nt*16 + l16]
                            = oacc[sub][nt][r];
            if (l16 == 0)
                #pragma unroll
                for (int sub = 0; sub < 4; ++sub)
                    #pragma unroll
                    for (int r = 0; r < 4; ++r)
                        LredF[(slot*4 + sub)*16 + quad*4 + r] = lacc[sub][r];
        }
        __syncthreads();
        if (kvh == 0 && (qw >> 1) == t) {
            int slot = qw & 1;
            #pragma unroll
            for (int sub = 0; sub < 4; ++sub)
                #pragma unroll
                for (int nt = 0; nt < 4; ++nt)
                    #pragma unroll
                    for (int r = 0; r < 4; ++r)
                        oacc[sub][nt][r] +=
                            OredF[((slot*4 + sub)*16 + quad*4 + r)*64 + nt*16 + l16];
            if (l16 == 0)
                #pragma unroll
                for (int sub = 0; sub < 4; ++sub)
                    #pragma unroll
                    for (int r = 0; r < 4; ++r)
                        lacc[sub][r] += LredF[(slot*4 + sub)*16 + quad*4 + r];
            #pragma unroll
            for (int sub = 0; sub < 4; ++sub)
                #pragma unroll
                for (int r = 0; r < 4; ++r) {
                    float l = __shfl(lacc[sub][r], quad * 16, 64);
                    float inv = 1.0f / l;
                    int lq = qt*256 + qw*64 + sub*16 + quad*4 + r;
                    size_t rowbase = ((size_t)(b * 2048 + lq)) * DIM + h * 64;
                    #pragma unroll
                    for (int nt = 0; nt < 4; ++nt)
                        AO[rowbase + nt*16 + l16] = (bf16)(oacc[sub][nt][r] * inv);
                }
        }
    }
}

extern "C" void kernel_launch(void* const* d_in, const int* in_sizes, int n_in,
                              void* d_out, int out_size, void* d_ws, size_t ws_size,
                              hipStream_t stream) {
    const float* x      = (const float*)d_in[0];
    const float* w_qkv  = (const float*)d_in[1];
    const float* w_proj = (const float*)d_in[2];
    const float* b_proj = (const float*)d_in[3];
    float* out = (float*)d_out;
    char* ws = (char*)d_ws;

    bf16* xb  = (bf16*)(ws);                    // 8 MB
    bf16* wqb = (bf16*)(ws + ( 8u << 20));      // 6 MB
    bf16* wpb = (bf16*)(ws + (14u << 20));      // 2 MB
    bf16* Qb  = (bf16*)(ws + (16u << 20));      // 8 MB [bh][l][d]
    bf16* Kb  = (bf16*)(ws + (24u << 20));      // 8 MB [bh][l][d]
    bf16* VTb = (bf16*)(ws + (32u << 20));      // 8 MB [bh][d][l]
    bf16* AOb = (bf16*)(ws + (40u << 20));      // 8 MB [b*l][h*d]

    cvt_all<<<(C0 + C1 + C2) / 256, 256, 0, stream>>>(x, w_qkv, w_proj, xb, wqb, wpb);
    gemm_qkv<<<dim3(NQKV/128, BL/128), 256, 0, stream>>>(xb, wqb, Qb, Kb, VTb);
    attn<<<dim3(LL/256, BB*NH),        512, 0, stream>>>(Qb, Kb, VTb, AOb);
    gemm_proj<<<dim3(DIM/64, BL/128),  256, 0, stream>>>(AOb, wpb, b_proj, out);
}

// Round 10
// 168.967 us; speedup vs baseline: 2.7083x; 1.0157x over previous
//
#include <hip/hip_runtime.h>

#define DIM 1024
#define NH 16
#define HD 64
#define BB 2
#define LL 2048
#define BL (BB*LL)     // 4096
#define NQKV (3*DIM)   // 3072

typedef __bf16 bf16;
typedef __bf16 bf16x4 __attribute__((ext_vector_type(4)));
typedef __bf16 bf16x8 __attribute__((ext_vector_type(8)));
typedef float  f32x4  __attribute__((ext_vector_type(4)));

// 0.125 * log2(e): fold head-dim scale + base-2 conversion into Q
#define QSCALE 0.1803368801111204f

typedef __attribute__((address_space(3))) unsigned int lds_u32;
typedef __attribute__((address_space(1))) unsigned int glb_u32;

// async global->LDS, 16B per lane. LDS dest = wave-uniform base + lane*16.
__device__ __forceinline__ void gld_lds16(const bf16* g, bf16* l) {
    __builtin_amdgcn_global_load_lds((const glb_u32*)g, (lds_u32*)l, 16, 0, 0);
}

// One kernel for all three fp32->bf16 conversions.
#define C0 (BL*DIM/4)      // x     : 1048576 float4
#define C1 (NQKV*DIM/4)    // w_qkv :  786432
#define C2 (DIM*DIM/4)     // w_proj:  262144
__global__ __launch_bounds__(256) void cvt_all(const float* __restrict__ x,
        const float* __restrict__ wq, const float* __restrict__ wp,
        bf16* __restrict__ xb, bf16* __restrict__ wqb, bf16* __restrict__ wpb) {
    int i = blockIdx.x * 256 + threadIdx.x;
    const float* in; bf16* out; int j;
    if (i < C0)            { in = x;  out = xb;  j = i; }
    else if (i < C0 + C1)  { in = wq; out = wqb; j = i - C0; }
    else                   { in = wp; out = wpb; j = i - C0 - C1; }
    float4 f = ((const float4*)in)[j];
    bf16x4 o = { (bf16)f.x, (bf16)f.y, (bf16)f.z, (bf16)f.w };
    ((bf16x4*)out)[j] = o;
}

// QKV GEMM: 128x128 tile, BK=64, XOR-swizzled LDS, operand-swapped MFMA
// (A-op = W rows) -> vectorized Q/K stores, lane-contiguous V stores.
// 768 blocks = 3/CU: cross-block overlap covers the barrier drain (m97).
__global__ __launch_bounds__(256, 3) void gemm_qkv(
        const bf16* __restrict__ A, const bf16* __restrict__ W,
        bf16* __restrict__ Qb, bf16* __restrict__ Kb, bf16* __restrict__ VTb) {
    __shared__ bf16 As[128][64];   // x tile, swizzled: LDS[r][c] = glb[r][c^(r&7)]
    __shared__ bf16 Bs[128][64];   // W tile, swizzled
    const int tid = threadIdx.x;
    const int w = tid >> 6, lane = tid & 63, quad = lane >> 4, l16 = lane & 15;
    const int n0 = blockIdx.x * 128, m0 = blockIdx.y * 128;
    const int wm = (w & 1) * 64, wn = (w >> 1) * 64;
    f32x4 acc[4][4] = {};   // acc[tm(n)][tn(m)]
    for (int k0 = 0; k0 < DIM; k0 += 64) {
        #pragma unroll
        for (int i = 0; i < 4; ++i) {        // 1024 chunks per tensor, 4/thread
            int cb = w * 256 + i * 64;       // wave-uniform chunk base
            int gc = cb + lane;
            int r = gc >> 3;
            int cs = (gc & 7) ^ (r & 7);     // swizzled source chunk
            gld_lds16(A + (size_t)(m0 + r) * DIM + k0 + cs*8, &As[0][0] + cb * 8);
            gld_lds16(W + (size_t)(n0 + r) * DIM + k0 + cs*8, &Bs[0][0] + cb * 8);
        }
        __syncthreads();
        #pragma unroll
        for (int kc = 0; kc < 2; ++kc) {
            bf16x8 af[4], bfr[4];
            #pragma unroll
            for (int t = 0; t < 4; ++t) {
                int rw = wn + t*16 + l16;                 // W row (n)
                int cw = (kc*4 + quad) ^ (rw & 7);
                af[t] = *(const bf16x8*)(&Bs[0][0] + rw*64 + cw*8);
                int rx = wm + t*16 + l16;                 // x row (m)
                int cx = (kc*4 + quad) ^ (rx & 7);
                bfr[t] = *(const bf16x8*)(&As[0][0] + rx*64 + cx*8);
            }
            #pragma unroll
            for (int tm = 0; tm < 4; ++tm)
                #pragma unroll
                for (int tn = 0; tn < 4; ++tn)
                    acc[tm][tn] = __builtin_amdgcn_mfma_f32_16x16x32_bf16(
                                      af[tm], bfr[tn], acc[tm][tn], 0, 0, 0);
        }
        __syncthreads();
    }
    // D layout (swapped): row quad*4+r -> n, col l16 -> m
    const int which = n0 >> 10;   // uniform per block
    #pragma unroll
    for (int tm = 0; tm < 4; ++tm) {
        int nb = n0 + wn + tm*16 + quad*4;       // n base for this lane (r=0..3)
        int rem = nb & 1023, h = rem >> 6, db = rem & 63;
        #pragma unroll
        for (int tn = 0; tn < 4; ++tn) {
            int m = m0 + wm + tn*16 + l16;
            int b = m >> 11, l = m & 2047, bh = (b << 4) | h;
            if (which == 0) {
                bf16x4 q4 = { (bf16)(acc[tm][tn][0] * QSCALE),
                              (bf16)(acc[tm][tn][1] * QSCALE),
                              (bf16)(acc[tm][tn][2] * QSCALE),
                              (bf16)(acc[tm][tn][3] * QSCALE) };
                *(bf16x4*)(Qb + ((size_t)bh << 17) + ((size_t)l << 6) + db) = q4;
            } else if (which == 1) {
                bf16x4 k4 = { (bf16)acc[tm][tn][0], (bf16)acc[tm][tn][1],
                              (bf16)acc[tm][tn][2], (bf16)acc[tm][tn][3] };
                *(bf16x4*)(Kb + ((size_t)bh << 17) + ((size_t)l << 6) + db) = k4;
            } else {
                #pragma unroll
                for (int r = 0; r < 4; ++r)   // lanes contiguous in l: 32B chunks
                    VTb[((size_t)bh << 17) + ((size_t)(db + r) << 11) + l] =
                        (bf16)acc[tm][tn][r];
            }
        }
    }
}

// proj: 128(M)x64(N), BK=64, swizzled, operand-swapped, DOUBLE-BUFFERED with
// 1-iter lookahead: stage(t+1) issues right after the barrier, compute(t)
// runs from the other buffer. One barrier per K-step. 512 blocks = 2/CU.
__global__ __launch_bounds__(256, 3) void gemm_proj(
        const bf16* __restrict__ A, const bf16* __restrict__ W,
        const float* __restrict__ bias, float* __restrict__ out) {
    __shared__ bf16 As[2][128][64];   // 32 KB
    __shared__ bf16 Bs[2][64][64];    // 16 KB
    const int tid = threadIdx.x;
    const int w = tid >> 6, lane = tid & 63, quad = lane >> 4, l16 = lane & 15;
    const int n0 = blockIdx.x * 64, m0 = blockIdx.y * 128;
    const int wm = (w & 1) * 64, wn = (w >> 1) * 32;
    f32x4 acc[2][4] = {};   // acc[tm(n)][tn(m)]

    auto stage = [&](int k0, int buf) {
        #pragma unroll
        for (int i = 0; i < 4; ++i) {        // A: 1024 chunks, 4/thread
            int cb = w * 256 + i * 64;
            int gc = cb + lane;
            int r = gc >> 3;
            int cs = (gc & 7) ^ (r & 7);
            gld_lds16(A + (size_t)(m0 + r) * DIM + k0 + cs*8,
                      &As[buf][0][0] + cb * 8);
        }
        #pragma unroll
        for (int i = 0; i < 2; ++i) {        // B: 512 chunks, 2/thread
            int cb = w * 128 + i * 64;
            int gc = cb + lane;
            int r = gc >> 3;
            int cs = (gc & 7) ^ (r & 7);
            gld_lds16(W + (size_t)(n0 + r) * DIM + k0 + cs*8,
                      &Bs[buf][0][0] + cb * 8);
        }
    };

    stage(0, 0);
    for (int ks = 0; ks < 16; ++ks) {
        const int cur = ks & 1;
        __syncthreads();                  // stage(ks) landed; buf^1 reads done
        if (ks < 15) stage((ks + 1) * 64, cur ^ 1);
        #pragma unroll
        for (int kc = 0; kc < 2; ++kc) {
            bf16x8 af[2], bfr[4];
            #pragma unroll
            for (int t = 0; t < 2; ++t) {
                int rw = wn + t*16 + l16;
                int cw = (kc*4 + quad) ^ (rw & 7);
                af[t] = *(const bf16x8*)(&Bs[cur][0][0] + rw*64 + cw*8);
            }
            #pragma unroll
            for (int t = 0; t < 4; ++t) {
                int rx = wm + t*16 + l16;
                int cx = (kc*4 + quad) ^ (rx & 7);
                bfr[t] = *(const bf16x8*)(&As[cur][0][0] + rx*64 + cx*8);
            }
            #pragma unroll
            for (int tm = 0; tm < 2; ++tm)
                #pragma unroll
                for (int tn = 0; tn < 4; ++tn)
                    acc[tm][tn] = __builtin_amdgcn_mfma_f32_16x16x32_bf16(
                                      af[tm], bfr[tn], acc[tm][tn], 0, 0, 0);
        }
    }
    #pragma unroll
    for (int tm = 0; tm < 2; ++tm) {
        int nb = n0 + wn + tm*16 + quad*4;
        float4 b4 = *(const float4*)&bias[nb];
        #pragma unroll
        for (int tn = 0; tn < 4; ++tn) {
            int m = m0 + wm + tn*16 + l16;
            float4 o4 = { acc[tm][tn][0] + b4.x, acc[tm][tn][1] + b4.y,
                          acc[tm][tn][2] + b4.z, acc[tm][tn][3] + b4.w };
            *(float4*)(out + (size_t)m * DIM + nb) = o4;
        }
    }
}

// Flash attention, QBLK=256 / 8 waves / kv-split / KVBLK=128: two 64-row
// kv-subtiles per barrier (R5 configuration -- session best, 164.06 us).
// Body order stage -> PV(kt-1) -> S(kt) -> exp(kt): R9 proved the
// S-before-PV reorder raises util counters but extends S-register lifetimes
// (VGPR 96->128) for zero wall gain. Ks/VTs are [buf][sub][64][64]; each
// subtile keeps the verified swizzles; a wave's kv-half = subtile kvh with
// kk in {0,1} selecting the 32-wide k-block inside it.
__global__ __launch_bounds__(512, 2) void attn(
        const bf16* __restrict__ Qb, const bf16* __restrict__ Kb,
        const bf16* __restrict__ VTb, bf16* __restrict__ AO) {
    __shared__ __align__(16) char smem[66048];   // Ks 32KB | VTs 32KB | Lred
    bf16* KsP  = (bf16*)smem;                    // [buf][sub][64][64]
    bf16* VTsP = (bf16*)(smem + 32768);          // [buf][sub][64][64]
    const int tid = threadIdx.x;
    const int w = tid >> 6, lane = tid & 63, quad = lane >> 4, l16 = lane & 15;
    const int qw = w & 3, kvh = w >> 2;          // q-quarter, kv-half
    // Bijective XCD swizzle (nwg=256, 256%8==0): XCD x gets bh in [4x, 4x+3].
    const int linear = blockIdx.y * 8 + blockIdx.x;
    const int swz = (linear & 7) * 32 + (linear >> 3);
    const int qt = swz & 7, bh = swz >> 3;
    const bf16* Qg = Qb + ((size_t)bh << 17) + (size_t)(qt * 256) * 64;
    const bf16* Kg = Kb + ((size_t)bh << 17);
    const bf16* Vg = VTb + ((size_t)bh << 17);

    bf16x8 aq[4][2];   // aq[sub][kd]: Q[q=qw*64+sub*16+l16][d=kd*32+quad*8+..]
    #pragma unroll
    for (int sub = 0; sub < 4; ++sub)
        #pragma unroll
        for (int kd = 0; kd < 2; ++kd)
            aq[sub][kd] = *(const bf16x8*)(Qg + (size_t)(qw*64 + sub*16 + l16) * 64
                                           + kd*32 + quad*8);

    bf16x8 onesf = {};
    if (l16 == 0)
        #pragma unroll
        for (int j = 0; j < 8; ++j) onesf[j] = (bf16)1.0f;

    f32x4 oacc[4][4] = {};         // [sub][nt]: O[q=sub*16+quad*4+r][d=nt*16+l16]
    f32x4 lacc[4] = {};            // row-sums, valid at l16==0 lanes
    const f32x4 zero4 = {};
    bf16x8 ap[4][2];               // P regs: [sub][kk], packed kt, PV'd kt+1

    // 512 threads stage one 16B chunk per subtile (2 subtiles per tensor).
    auto stageK = [&](int kt, int buf) {
        #pragma unroll
        for (int sub = 0; sub < 2; ++sub) {
            int r = tid >> 3;
            int cs = (tid & 7) ^ (r & 7) ^ ((r >> 3) & 7) ^ ((r & 1) << 2); // fK
            gld_lds16(Kg + (size_t)(kt*128 + sub*64 + r) * 64 + cs*8,
                      KsP + (buf*2 + sub) * 4096 + tid*8);
        }
    };
    auto stageV = [&](int kt, int buf) {
        #pragma unroll
        for (int sub = 0; sub < 2; ++sub) {
            int r = tid >> 3;
            int cs = (tid & 7) ^ (r & 7) ^ ((r >> 3) & 7);                  // fV
            gld_lds16(Vg + (size_t)r * 2048 + kt*128 + sub*64 + cs*8,
                      VTsP + (buf*2 + sub) * 4096 + tid*8);
        }
    };
    // PV for register P-frags 'ap' (this wave's kv-half = subtile kvh)
    auto pv = [&](int pbuf) {
        __builtin_amdgcn_s_setprio(1);
        #pragma unroll
        for (int kk = 0; kk < 2; ++kk) {
            #pragma unroll
            for (int nt = 0; nt < 4; ++nt) {
                int row = nt*16 + l16;                      // d-dim row of VT
                int cp = (kk*4 + quad) ^ (row & 7) ^ ((row >> 3) & 7);
                bf16x8 bv = *(const bf16x8*)(VTsP + (pbuf*2 + kvh) * 4096
                                             + row*64 + cp*8);
                #pragma unroll
                for (int sub = 0; sub < 4; ++sub)
                    oacc[sub][nt] = __builtin_amdgcn_mfma_f32_16x16x32_bf16(
                                        ap[sub][kk], bv, oacc[sub][nt], 0, 0, 0);
            }
            #pragma unroll
            for (int sub = 0; sub < 4; ++sub)
                lacc[sub] = __builtin_amdgcn_mfma_f32_16x16x32_bf16(
                                ap[sub][kk], onesf, lacc[sub], 0, 0, 0);
        }
        __builtin_amdgcn_s_setprio(0);
    };

    // One pipeline step (128 kv). Barrier: K(kt)+V(kt-1) staging landed (loads
    // issued a full iteration ago); reads of buffers being overwritten done.
    auto body = [&](int kt, int cur) {
        __syncthreads();
        if (kt < 15) stageK(kt + 1, cur ^ 1);
        stageV(kt, cur);                      // read at iter kt+1 (or epilogue)

        // PV(kt-1): register P (old ap) + VTs[cur^1]
        if (kt > 0) pv(cur ^ 1);

        // S^T(kt) from Ks[cur][kvh]: A = K-frag (permuted rows), B = aq
        f32x4 s[4][2][2];   // [sub][kk][u]
        __builtin_amdgcn_s_setprio(1);
        #pragma unroll
        for (int kk = 0; kk < 2; ++kk)
            #pragma unroll
            for (int u = 0; u < 2; ++u) {
                int rk = kk*32 + ((l16 >> 2) << 3) + u*4 + (l16 & 3);
                int f = (rk & 7) ^ ((rk >> 3) & 7) ^ ((rk & 1) << 2);
                const bf16* kb = KsP + (cur*2 + kvh) * 4096 + rk*64;
                bf16x8 kf0 = *(const bf16x8*)(kb + ((0*4 + quad) ^ f)*8);
                bf16x8 kf1 = *(const bf16x8*)(kb + ((1*4 + quad) ^ f)*8);
                #pragma unroll
                for (int sub = 0; sub < 4; ++sub) {
                    s[sub][kk][u] = __builtin_amdgcn_mfma_f32_16x16x32_bf16(
                                        kf0, aq[sub][0], zero4, 0, 0, 0);
                    s[sub][kk][u] = __builtin_amdgcn_mfma_f32_16x16x32_bf16(
                                        kf1, aq[sub][1], s[sub][kk][u], 0, 0, 0);
                }
            }
        __builtin_amdgcn_s_setprio(0);

        // exp2 + pack P(kt); lane (quad,l16) holds
        // P[q=l16][kv = kvh*64 + kk*32 + quad*8 + u*4 + r].
        #pragma unroll
        for (int sub = 0; sub < 4; ++sub)
            #pragma unroll
            for (int kk = 0; kk < 2; ++kk) {
                bf16x8 p;
                #pragma unroll
                for (int u = 0; u < 2; ++u)
                    #pragma unroll
                    for (int r = 0; r < 4; ++r)
                        p[u*4 + r] = (bf16)__builtin_amdgcn_exp2f(s[sub][kk][u][r]);
                ap[sub][kk] = p;
            }
    };

    stageK(0, 0);
    for (int kt2 = 0; kt2 < 16; kt2 += 2) {
        body(kt2,     0);
        body(kt2 + 1, 1);
    }
    __syncthreads();   // V(15) staging landed for all waves
    pv(1);             // final PV(15)

    // Combine kv-halves: wave w+4 adds into wave w via LDS (staging reuse).
    // Two rounds of 2 writer-waves (2 x 16KB = 32KB fits the K region).
    float* OredF = (float*)smem;            // [slot2][sub4][row16][d64]
    float* LredF = (float*)(smem + 32768);  // [slot2][sub4][row16]
    const int b = bh >> 4, h = bh & 15;
    #pragma unroll
    for (int t = 0; t < 2; ++t) {
        __syncthreads();
        if (kvh == 1 && (qw >> 1) == t) {
            int slot = qw & 1;
            #pragma unroll
            for (int sub = 0; sub < 4; ++sub)
                #pragma unroll
                for (int nt = 0; nt < 4; ++nt)
                    #pragma unroll
                    for (int r = 0; r < 4; ++r)
                        OredF[((slot*4 + sub)*16 + quad*4 + r)*64 + nt*16 + l16]
                            = oacc[sub][nt][r];
            if (l16 == 0)
                #pragma unroll
                for (int sub = 0; sub < 4; ++sub)
                    #pragma unroll
                    for (int r = 0; r < 4; ++r)
                        LredF[(slot*4 + sub)*16 + quad*4 + r] = lacc[sub][r];
        }
        __syncthreads();
        if (kvh == 0 && (qw >> 1) == t) {
            int slot = qw & 1;
            #pragma unroll
            for (int sub = 0; sub < 4; ++sub)
                #pragma unroll
                for (int nt = 0; nt < 4; ++nt)
                    #pragma unroll
                    for (int r = 0; r < 4; ++r)
                        oacc[sub][nt][r] +=
                            OredF[((slot*4 + sub)*16 + quad*4 + r)*64 + nt*16 + l16];
            if (l16 == 0)
                #pragma unroll
                for (int sub = 0; sub < 4; ++sub)
                    #pragma unroll
                    for (int r = 0; r < 4; ++r)
                        lacc[sub][r] += LredF[(slot*4 + sub)*16 + quad*4 + r];
            #pragma unroll
            for (int sub = 0; sub < 4; ++sub)
                #pragma unroll
                for (int r = 0; r < 4; ++r) {
                    float l = __shfl(lacc[sub][r], quad * 16, 64);
                    float inv = 1.0f / l;
                    int lq = qt*256 + qw*64 + sub*16 + quad*4 + r;
                    size_t rowbase = ((size_t)(b * 2048 + lq)) * DIM + h * 64;
                    #pragma unroll
                    for (int nt = 0; nt < 4; ++nt)
                        AO[rowbase + nt*16 + l16] = (bf16)(oacc[sub][nt][r] * inv);
                }
        }
    }
}

extern "C" void kernel_launch(void* const* d_in, const int* in_sizes, int n_in,
                              void* d_out, int out_size, void* d_ws, size_t ws_size,
                              hipStream_t stream) {
    const float* x      = (const float*)d_in[0];
    const float* w_qkv  = (const float*)d_in[1];
    const float* w_proj = (const float*)d_in[2];
    const float* b_proj = (const float*)d_in[3];
    float* out = (float*)d_out;
    char* ws = (char*)d_ws;

    bf16* xb  = (bf16*)(ws);                    // 8 MB
    bf16* wqb = (bf16*)(ws + ( 8u << 20));      // 6 MB
    bf16* wpb = (bf16*)(ws + (14u << 20));      // 2 MB
    bf16* Qb  = (bf16*)(ws + (16u << 20));      // 8 MB [bh][l][d]
    bf16* Kb  = (bf16*)(ws + (24u << 20));      // 8 MB [bh][l][d]
    bf16* VTb = (bf16*)(ws + (32u << 20));      // 8 MB [bh][d][l]
    bf16* AOb = (bf16*)(ws + (40u << 20));      // 8 MB [b*l][h*d]

    cvt_all<<<(C0 + C1 + C2) / 256, 256, 0, stream>>>(x, w_qkv, w_proj, xb, wqb, wpb);
    gemm_qkv<<<dim3(NQKV/128, BL/128), 256, 0, stream>>>(xb, wqb, Qb, Kb, VTb);
    attn<<<dim3(LL/256, BB*NH),        512, 0, stream>>>(Qb, Kb, VTb, AOb);
    gemm_proj<<<dim3(DIM/64, BL/128),  256, 0, stream>>>(AOb, wpb, b_proj, out);
}